// Round 2
// baseline (358.167 us; speedup 1.0000x reference)
//
#include <hip/hip_runtime.h>
#include <hip/hip_bf16.h>

// Conv2DAttentionBlock: B=16, C=128, HW=1024, 4 heads x d=128 attention + 1x1 convs.
// All GEMM-shaped stages in bf16 MFMA (16x16x32), fp32 accumulate.
// Workspace layout (needs 71,827,456 bytes):
//   wqkv  bf16[1536][128]           @ 0
//   wtb   bf16[128][512]            @ 393216
//   xt    bf16[16][1024][128]       @ 524288      (x transposed, n-major)
//   Qt    bf16[16][4][1024][128]    @ 4718592     (n-major)
//   Kt    bf16[16][4][1024][128]    @ 21495808    (m-major)
//   Vd    bf16[16][4][128][1024]    @ 38273024    (d-major)
//   Oscr  bf16[16][1024][512]       @ 55050240    (scrambled-transposed attn out)

#define NB 16
#define CD 128
#define HWN 1024
#define NH 4

typedef __attribute__((ext_vector_type(8))) short bf16x8;
typedef __attribute__((ext_vector_type(4))) short bf16x4;
typedef __attribute__((ext_vector_type(4))) float f32x4;

static __device__ __forceinline__ short f2bf(float f) {
  union { float f; unsigned u; } v; v.f = f;
  unsigned r = v.u + 0x7fffu + ((v.u >> 16) & 1u);  // RNE
  return (short)(r >> 16);
}

// ---- weights: fp32 -> bf16 (Wq,Wk,Wv concat rows; Wt as-is) -------------
__global__ void cvt_weights(const float* __restrict__ Wq, const float* __restrict__ Wk,
                            const float* __restrict__ Wv, const float* __restrict__ Wt,
                            short* __restrict__ wqkv, short* __restrict__ wtb) {
  int i = blockIdx.x * 256 + threadIdx.x;  // grid covers exactly 65536
  wqkv[i]          = f2bf(Wq[i]);
  wqkv[i + 65536]  = f2bf(Wk[i]);
  wqkv[i + 131072] = f2bf(Wv[i]);
  wtb[i]           = f2bf(Wt[i]);
}

// ---- x[b][c][n] fp32 -> xt[b][n][c] bf16 (LDS tile transpose) -----------
__global__ void cvt_transpose_x(const float* __restrict__ x, short* __restrict__ xt) {
  __shared__ short tile[32][33];
  int b = blockIdx.z, c0 = blockIdx.y * 32, n0 = blockIdx.x * 32;
  int tx = threadIdx.x & 31, ty = threadIdx.x >> 5;  // 32x8
  const float* xp = x + ((size_t)b * CD + c0) * HWN + n0;
  for (int k = 0; k < 4; ++k)
    tile[ty + 8 * k][tx] = f2bf(xp[(size_t)(ty + 8 * k) * HWN + tx]);
  __syncthreads();
  short* xo = xt + ((size_t)b * HWN + n0) * CD + c0;
  for (int k = 0; k < 4; ++k)
    xo[(size_t)(ty + 8 * k) * CD + tx] = tile[tx][ty + 8 * k];
}

// ---- QKV: Y[o][n] = sum_c Wqkv[o][c] * x[c][n]; scatter to Qt/Kt/Vd -----
// MFMA: i=o, j=n, k=c. Wave computes 16o x 128n, K=128.
__launch_bounds__(256)
__global__ void qkv_gemm(const short* __restrict__ wqkv, const short* __restrict__ xt,
                         const float* __restrict__ bv,
                         short* __restrict__ Qt, short* __restrict__ Kt,
                         short* __restrict__ Vd) {
  int b = blockIdx.z;
  int wave = threadIdx.x >> 6, lane = threadIdx.x & 63;
  int l15 = lane & 15, l4 = lane >> 4;
  int o0 = blockIdx.y * 64 + wave * 16;   // gridDim.y = 24
  int n0 = blockIdx.x * 128;              // gridDim.x = 8

  bf16x8 afrag[4];
  for (int kt = 0; kt < 4; ++kt)
    afrag[kt] = *(const bf16x8*)(wqkv + (size_t)(o0 + l15) * CD + kt * 32 + l4 * 8);

  f32x4 acc[8];
  for (int jt = 0; jt < 8; ++jt) acc[jt] = (f32x4){0.f, 0.f, 0.f, 0.f};

  const short* xb = xt + (size_t)b * HWN * CD;
  for (int jt = 0; jt < 8; ++jt) {
    int n = n0 + jt * 16 + l15;
    for (int kt = 0; kt < 4; ++kt) {
      bf16x8 bfrag = *(const bf16x8*)(xb + (size_t)n * CD + kt * 32 + l4 * 8);
      acc[jt] = __builtin_amdgcn_mfma_f32_16x16x32_bf16(afrag[kt], bfrag, acc[jt], 0, 0, 0);
    }
  }

  if (o0 < 1024) {  // Q or K -> [b][h][n][d], 4 consecutive d per lane -> 8B store
    short* dst = (o0 < 512) ? Qt : Kt;
    int oo = (o0 < 512) ? o0 : o0 - 512;
    int h = oo >> 7, d0 = (oo & 127) + l4 * 4;
    for (int jt = 0; jt < 8; ++jt) {
      int n = n0 + jt * 16 + l15;
      bf16x4 v4;
      for (int r = 0; r < 4; ++r) v4[r] = f2bf(acc[jt][r]);
      *(bf16x4*)(dst + (((size_t)b * NH + h) * HWN + n) * CD + d0) = v4;
    }
  } else {          // V -> [b][h][d][m] (+bv), scattered 2B stores
    int oo = o0 - 1024;
    int h = oo >> 7, d0 = (oo & 127) + l4 * 4;
    float bvv[4];
    for (int r = 0; r < 4; ++r) bvv[r] = bv[oo + l4 * 4 + r];
    for (int jt = 0; jt < 8; ++jt) {
      int n = n0 + jt * 16 + l15;
      for (int r = 0; r < 4; ++r)
        Vd[(((size_t)b * NH + h) * CD + d0 + r) * HWN + n] = f2bf(acc[jt][r] + bvv[r]);
    }
  }
}

// ---- flash attention per (b,h): S=1024, D=128 ---------------------------
// Wave owns 16 Q-rows; KVBLK=64; swapped QK^T (S^T = K x Q) so each lane
// holds 16 scores of ONE q-row (n = lane&15) -> in-register softmax stats,
// only 2 shfl_xor per reduction. Defer-max (THR=8, log2 domain). P staged
// via LDS subtile layout [ks][g][n][8]: b64 writes / b128 reads, balanced
// banks. Parity double-buffer.
__launch_bounds__(256)
__global__ void attn(const short* __restrict__ Qt, const short* __restrict__ Kt,
                     const short* __restrict__ Vd, short* __restrict__ Oscr) {
  int b = blockIdx.z, h = blockIdx.y;
  int wave = threadIdx.x >> 6, lane = threadIdx.x & 63;
  int l15 = lane & 15, l4 = lane >> 4;
  int n0 = blockIdx.x * 64 + wave * 16;   // gridDim.x = 16
  size_t bh = (size_t)b * NH + h;
  const short* q = Qt + bh * HWN * CD;
  const short* k = Kt + bh * HWN * CD;
  const short* v = Vd + bh * CD * HWN;

  // pl[wave][parity][ks][g][n][e] : P[n][32*ks + 8*g + e]
  __shared__ short pl[4][2][2][4][16][8];

  bf16x8 bq[4];  // Q as B-fragment: col = n = l15, k = c
  for (int kt = 0; kt < 4; ++kt)
    bq[kt] = *(const bf16x8*)(q + (size_t)(n0 + l15) * CD + kt * 32 + l4 * 8);

  f32x4 oacc[8];
  for (int jt = 0; jt < 8; ++jt) oacc[jt] = (f32x4){0.f, 0.f, 0.f, 0.f};
  float mi = -1e30f, li = 0.f;

  const float SC = 0.08838834764831845f * 1.44269504088896341f;  // 1/sqrt(128)*log2(e)

  for (int mt = 0; mt < 16; ++mt) {
    int m0 = mt * 64;
    // QK^T swapped: s[t] = S^T[m0+16t+l4*4+r][n0+l15]
    f32x4 s[4];
    for (int t = 0; t < 4; ++t) s[t] = (f32x4){0.f, 0.f, 0.f, 0.f};
    for (int kt = 0; kt < 4; ++kt) {
      for (int t = 0; t < 4; ++t) {
        bf16x8 ak = *(const bf16x8*)(k + (size_t)(m0 + t * 16 + l15) * CD + kt * 32 + l4 * 8);
        s[t] = __builtin_amdgcn_mfma_f32_16x16x32_bf16(ak, bq[kt], s[t], 0, 0, 0);
      }
    }
    // scores in log2 domain; lane holds 16 values of row n = l15
    float al[4][4];
    float mx4[4];
    for (int t = 0; t < 4; ++t) {
      for (int r = 0; r < 4; ++r) al[t][r] = s[t][r] * SC;
      mx4[t] = fmaxf(fmaxf(al[t][0], al[t][1]), fmaxf(al[t][2], al[t][3]));
    }
    float mx = fmaxf(fmaxf(mx4[0], mx4[1]), fmaxf(mx4[2], mx4[3]));
    mx = fmaxf(mx, __shfl_xor(mx, 16));
    mx = fmaxf(mx, __shfl_xor(mx, 32));  // full row max, replicated over l4

    float p[4][4];
    if (__all(mx - mi <= 8.0f)) {
      // deferred: keep old max, P bounded by 2^8, no O-rescale
      for (int t = 0; t < 4; ++t)
        for (int r = 0; r < 4; ++r) p[t][r] = __builtin_amdgcn_exp2f(al[t][r] - mi);
    } else {
      float nm = fmaxf(mi, mx);
      float fac = __builtin_amdgcn_exp2f(mi - nm);
      for (int t = 0; t < 4; ++t)
        for (int r = 0; r < 4; ++r) p[t][r] = __builtin_amdgcn_exp2f(al[t][r] - nm);
      li *= fac;
      mi = nm;
      float facb[4];
      for (int r = 0; r < 4; ++r)
        facb[r] = __shfl(fac, (lane & 48) | (l4 * 4 + r));  // fac for O-row l4*4+r
      for (int jt = 0; jt < 8; ++jt)
        for (int r = 0; r < 4; ++r) oacc[jt][r] *= facb[r];
    }
    float sm4[4];
    for (int t = 0; t < 4; ++t)
      sm4[t] = (p[t][0] + p[t][1]) + (p[t][2] + p[t][3]);
    float ls = (sm4[0] + sm4[1]) + (sm4[2] + sm4[3]);
    ls += __shfl_xor(ls, 16);
    ls += __shfl_xor(ls, 32);
    li += ls;

    // P -> LDS: chunk t holds P[n=l15][m = 16t + 4*l4 + r]
    int par = mt & 1;
    for (int t = 0; t < 4; ++t) {
      bf16x4 c4;
      for (int r = 0; r < 4; ++r) c4[r] = f2bf(p[t][r]);
      *(bf16x4*)&pl[wave][par][t >> 1][2 * (t & 1) + (l4 >> 1)][l15][4 * (l4 & 1)] = c4;
    }
    asm volatile("s_waitcnt lgkmcnt(0)" ::: "memory");  // intra-wave LDS W->R order
    bf16x8 ap0 = *(const bf16x8*)&pl[wave][par][0][l4][l15][0];
    bf16x8 ap1 = *(const bf16x8*)&pl[wave][par][1][l4][l15][0];
    for (int jt = 0; jt < 8; ++jt) {
      const short* vr = v + (size_t)(jt * 16 + l15) * HWN + m0 + l4 * 8;
      bf16x8 bv0 = *(const bf16x8*)(vr);
      bf16x8 bv1 = *(const bf16x8*)(vr + 32);
      oacc[jt] = __builtin_amdgcn_mfma_f32_16x16x32_bf16(ap0, bv0, oacc[jt], 0, 0, 0);
      oacc[jt] = __builtin_amdgcn_mfma_f32_16x16x32_bf16(ap1, bv1, oacc[jt], 0, 0, 0);
    }
  }

  // epilogue: O[n][d]/l -> Oscr[b][m=(n%8)*128+d][o=h*128+n/8]  (bijective)
  float inv = 1.0f / li;  // for row n = l15, replicated over l4
  float invb[4];
  for (int r = 0; r < 4; ++r)
    invb[r] = __shfl(inv, (lane & 48) | (l4 * 4 + r));
  for (int jt = 0; jt < 8; ++jt) {
    int d = jt * 16 + l15;
    for (int r = 0; r < 4; ++r) {
      int n = n0 + l4 * 4 + r;
      int o = h * CD + (n >> 3);
      int msp = (n & 7) * CD + d;
      Oscr[((size_t)b * HWN + msp) * 512 + o] = f2bf(oacc[jt][r] * invb[r]);
    }
  }
}

// ---- proj: out[b][c][m] = x + bt[c] + sum_o Wt[c][o]*OscrT[m][o] --------
// MFMA: i=m, j=c, k=o. Both operands k-contiguous; float4 output stores.
__launch_bounds__(256)
__global__ void proj_kernel(const short* __restrict__ Oscr, const short* __restrict__ wtb,
                            const float* __restrict__ bt, const float* __restrict__ x,
                            float* __restrict__ out) {
  int b = blockIdx.y;
  int wave = threadIdx.x >> 6, lane = threadIdx.x & 63;
  int l15 = lane & 15, l4 = lane >> 4;
  int m0 = blockIdx.x * 64 + wave * 16;   // gridDim.x = 16

  f32x4 acc[8];
  for (int jt = 0; jt < 8; ++jt) acc[jt] = (f32x4){0.f, 0.f, 0.f, 0.f};

  const short* ob = Oscr + (size_t)b * HWN * 512;
  for (int kt = 0; kt < 16; ++kt) {
    bf16x8 a = *(const bf16x8*)(ob + (size_t)(m0 + l15) * 512 + kt * 32 + l4 * 8);
    for (int jt = 0; jt < 8; ++jt) {
      bf16x8 bw = *(const bf16x8*)(wtb + (size_t)(jt * 16 + l15) * 512 + kt * 32 + l4 * 8);
      acc[jt] = __builtin_amdgcn_mfma_f32_16x16x32_bf16(a, bw, acc[jt], 0, 0, 0);
    }
  }
  for (int jt = 0; jt < 8; ++jt) {
    int c = jt * 16 + l15;
    float btc = bt[c];
    size_t base = ((size_t)b * CD + c) * HWN + m0 + l4 * 4;
    f32x4 xr = *(const f32x4*)(x + base);
    f32x4 o;
    for (int r = 0; r < 4; ++r) o[r] = acc[jt][r] + xr[r] + btc;
    *(f32x4*)(out + base) = o;
  }
}

extern "C" void kernel_launch(void* const* d_in, const int* in_sizes, int n_in,
                              void* d_out, int out_size, void* d_ws, size_t ws_size,
                              hipStream_t stream) {
  const float* x  = (const float*)d_in[0];
  const float* Wq = (const float*)d_in[1];
  const float* Wk = (const float*)d_in[2];
  const float* Wv = (const float*)d_in[3];
  const float* bv = (const float*)d_in[4];
  const float* Wt = (const float*)d_in[5];
  const float* bt = (const float*)d_in[6];
  float* out = (float*)d_out;
  char* ws = (char*)d_ws;

  short* wqkv = (short*)(ws);
  short* wtb  = (short*)(ws + 393216);
  short* xt   = (short*)(ws + 524288);
  short* Qt   = (short*)(ws + 4718592);
  short* Kt   = (short*)(ws + 21495808);
  short* Vd   = (short*)(ws + 38273024);
  short* Oscr = (short*)(ws + 55050240);  // total 71827456 bytes

  hipLaunchKernelGGL(cvt_weights, dim3(256), dim3(256), 0, stream, Wq, Wk, Wv, Wt, wqkv, wtb);
  hipLaunchKernelGGL(cvt_transpose_x, dim3(32, 4, 16), dim3(256), 0, stream, x, xt);
  hipLaunchKernelGGL(qkv_gemm, dim3(8, 24, 16), dim3(256), 0, stream, wqkv, xt, bv, Qt, Kt, Vd);
  hipLaunchKernelGGL(attn, dim3(16, 4, 16), dim3(256), 0, stream, Qt, Kt, Vd, Oscr);
  hipLaunchKernelGGL(proj_kernel, dim3(16, 16), dim3(256), 0, stream, Oscr, wtb, bt, x, out);
}

// Round 3
// 185.597 us; speedup vs baseline: 1.9298x; 1.9298x over previous
//
#include <hip/hip_runtime.h>
#include <hip/hip_bf16.h>

// Conv2DAttentionBlock: B=16, C=128, HW=1024, 4 heads x d=128 attention + 1x1 convs.
// All GEMM-shaped stages in bf16 MFMA (16x16x32), fp32 accumulate.
// Workspace layout (needs 71,827,456 bytes):
//   wqkv  bf16[1536][128]           @ 0           (Wq rows pre-scaled by 1/sqrt(128)*log2e)
//   wtb   bf16[128][512]            @ 393216
//   xt    bf16[16][1024][128]       @ 524288      (x transposed, n-major)
//   Qt    bf16[16][4][1024][128]    @ 4718592     (n-major, pre-scaled)
//   Kt    bf16[16][4][1024][128]    @ 21495808    (m-major)
//   Vd    bf16[16][4][128][1024]    @ 38273024    (d-major)
//   Oscr  bf16[16][1024][512]       @ 55050240    (scrambled-transposed attn out)

#define NB 16
#define CD 128
#define HWN 1024
#define NH 4
#define KVB 64

typedef __attribute__((ext_vector_type(8))) short bf16x8;
typedef __attribute__((ext_vector_type(4))) short bf16x4;
typedef __attribute__((ext_vector_type(4))) float f32x4;

static __device__ __forceinline__ short f2bf(float f) {
  union { float f; unsigned u; } v; v.f = f;
  unsigned r = v.u + 0x7fffu + ((v.u >> 16) & 1u);  // RNE
  return (short)(r >> 16);
}

// ---- weights: fp32 -> bf16 (Wq scaled by softmax scale in log2 domain) --
__global__ void cvt_weights(const float* __restrict__ Wq, const float* __restrict__ Wk,
                            const float* __restrict__ Wv, const float* __restrict__ Wt,
                            short* __restrict__ wqkv, short* __restrict__ wtb) {
  const float SC = 0.08838834764831845f * 1.44269504088896341f;  // 1/sqrt(128)*log2(e)
  int i = blockIdx.x * 256 + threadIdx.x;  // grid covers exactly 65536
  wqkv[i]          = f2bf(Wq[i] * SC);
  wqkv[i + 65536]  = f2bf(Wk[i]);
  wqkv[i + 131072] = f2bf(Wv[i]);
  wtb[i]           = f2bf(Wt[i]);
}

// ---- x[b][c][n] fp32 -> xt[b][n][c] bf16 (LDS tile transpose) -----------
__global__ void cvt_transpose_x(const float* __restrict__ x, short* __restrict__ xt) {
  __shared__ short tile[32][33];
  int b = blockIdx.z, c0 = blockIdx.y * 32, n0 = blockIdx.x * 32;
  int tx = threadIdx.x & 31, ty = threadIdx.x >> 5;  // 32x8
  const float* xp = x + ((size_t)b * CD + c0) * HWN + n0;
  for (int k = 0; k < 4; ++k)
    tile[ty + 8 * k][tx] = f2bf(xp[(size_t)(ty + 8 * k) * HWN + tx]);
  __syncthreads();
  short* xo = xt + ((size_t)b * HWN + n0) * CD + c0;
  for (int k = 0; k < 4; ++k)
    xo[(size_t)(ty + 8 * k) * CD + tx] = tile[tx][ty + 8 * k];
}

// ---- QKV: Y[o][n] = sum_c Wqkv[o][c] * x[c][n]; scatter to Qt/Kt/Vd -----
__launch_bounds__(256)
__global__ void qkv_gemm(const short* __restrict__ wqkv, const short* __restrict__ xt,
                         const float* __restrict__ bv,
                         short* __restrict__ Qt, short* __restrict__ Kt,
                         short* __restrict__ Vd) {
  int b = blockIdx.z;
  int wave = threadIdx.x >> 6, lane = threadIdx.x & 63;
  int l15 = lane & 15, l4 = lane >> 4;
  int o0 = blockIdx.y * 64 + wave * 16;   // gridDim.y = 24
  int n0 = blockIdx.x * 128;              // gridDim.x = 8

  bf16x8 afrag[4];
  for (int kt = 0; kt < 4; ++kt)
    afrag[kt] = *(const bf16x8*)(wqkv + (size_t)(o0 + l15) * CD + kt * 32 + l4 * 8);

  f32x4 acc[8];
  for (int jt = 0; jt < 8; ++jt) acc[jt] = (f32x4){0.f, 0.f, 0.f, 0.f};

  const short* xb = xt + (size_t)b * HWN * CD;
  for (int jt = 0; jt < 8; ++jt) {
    int n = n0 + jt * 16 + l15;
    for (int kt = 0; kt < 4; ++kt) {
      bf16x8 bfrag = *(const bf16x8*)(xb + (size_t)n * CD + kt * 32 + l4 * 8);
      acc[jt] = __builtin_amdgcn_mfma_f32_16x16x32_bf16(afrag[kt], bfrag, acc[jt], 0, 0, 0);
    }
  }

  if (o0 < 1024) {  // Q or K -> [b][h][n][d]
    short* dst = (o0 < 512) ? Qt : Kt;
    int oo = (o0 < 512) ? o0 : o0 - 512;
    int h = oo >> 7, d0 = (oo & 127) + l4 * 4;
    for (int jt = 0; jt < 8; ++jt) {
      int n = n0 + jt * 16 + l15;
      bf16x4 v4;
      for (int r = 0; r < 4; ++r) v4[r] = f2bf(acc[jt][r]);
      *(bf16x4*)(dst + (((size_t)b * NH + h) * HWN + n) * CD + d0) = v4;
    }
  } else {          // V -> [b][h][d][m] (+bv), scattered 2B stores
    int oo = o0 - 1024;
    int h = oo >> 7, d0 = (oo & 127) + l4 * 4;
    float bvv[4];
    for (int r = 0; r < 4; ++r) bvv[r] = bv[oo + l4 * 4 + r];
    for (int jt = 0; jt < 8; ++jt) {
      int n = n0 + jt * 16 + l15;
      for (int r = 0; r < 4; ++r)
        Vd[(((size_t)b * NH + h) * CD + d0 + r) * HWN + n] = f2bf(acc[jt][r] + bvv[r]);
    }
  }
}

// ---- flash attention per (b,h): S=1024, D=128 ---------------------------
// 4 waves/block, wave owns 32 Q-rows (2 fragments). KVBLK=64. K staged
// cooperatively in LDS (double-buffered global_load_lds, XOR-swizzled via
// pre-swizzled global source). V read direct from global (L2-resident).
// Swapped QK^T -> in-register softmax (log2 domain, Q pre-scaled), defer-max.
// One __syncthreads per iteration (drains staging vmcnt).
__launch_bounds__(256, 2)
__global__ void attn(const short* __restrict__ Qt, const short* __restrict__ Kt,
                     const short* __restrict__ Vd, short* __restrict__ Oscr) {
  int b = blockIdx.z, h = blockIdx.y;
  int wave = threadIdx.x >> 6, lane = threadIdx.x & 63;
  int l15 = lane & 15, l4 = lane >> 4;
  int n0 = blockIdx.x * 128 + wave * 32;   // gridDim.x = 8
  size_t bh = (size_t)b * NH + h;
  const short* q = Qt + bh * HWN * CD;
  const short* k = Kt + bh * HWN * CD;
  const short* v = Vd + bh * CD * HWN;

  __shared__ short Kls[2][KVB * CD];          // 32 KB, rows XOR-swizzled (byte^=(row&7)<<4)
  __shared__ short pl[4][2][2][2][4][16][8];  // [wave][qf][par][ks][g][n][e] 32 KB

  // stage K tile (64x128 bf16 = 16KB) into Kls[buf]; 16 x 1KB insts over 4 waves.
  // LDS dest linear; global source pre-swizzled so LDS holds K[row][col^((row&7)<<4 bytes)].
#define STAGE(buf, m0s)                                                       \
  for (int j = 0; j < 4; ++j) {                                               \
    int ii = wave * 4 + j;                                                    \
    int row = ii * 4 + l4;                                                    \
    int scol = (l15 * 16) ^ ((row & 7) << 4);                                 \
    const short* gp = k + (size_t)((m0s) + row) * CD + (scol >> 1);           \
    __builtin_amdgcn_global_load_lds(                                         \
        (const __attribute__((address_space(1))) void*)gp,                    \
        (__attribute__((address_space(3))) void*)&Kls[buf][ii * 512],         \
        16, 0, 0);                                                            \
  }

  bf16x8 bq[2][4];  // Q as B-fragment (col = n, k = c), pre-scaled
  for (int qf = 0; qf < 2; ++qf)
    for (int kt = 0; kt < 4; ++kt)
      bq[qf][kt] = *(const bf16x8*)(q + (size_t)(n0 + qf * 16 + l15) * CD + kt * 32 + l4 * 8);

  f32x4 oacc[2][8];
  for (int qf = 0; qf < 2; ++qf)
    for (int jt = 0; jt < 8; ++jt) oacc[qf][jt] = (f32x4){0.f, 0.f, 0.f, 0.f};
  float mi[2] = {-1e30f, -1e30f}, li[2] = {0.f, 0.f};

  STAGE(0, 0)
  __syncthreads();

  for (int mt = 0; mt < 16; ++mt) {
    int m0 = mt * KVB;
    int cur = mt & 1;
    if (mt < 15) STAGE(cur ^ 1, m0 + KVB)

    // QK^T swapped: s[qf][t] = S^T[m0+16t+4*l4+r][n0+16qf+l15]; K from LDS (swizzled read)
    f32x4 s[2][4];
    for (int qf = 0; qf < 2; ++qf)
      for (int t = 0; t < 4; ++t) s[qf][t] = (f32x4){0.f, 0.f, 0.f, 0.f};
    for (int kt = 0; kt < 4; ++kt)
      for (int t = 0; t < 4; ++t) {
        int row = t * 16 + l15;
        bf16x8 ak = *(const bf16x8*)&Kls[cur][row * CD + ((kt * 32 + l4 * 8) ^ ((l15 & 7) << 3))];
        s[0][t] = __builtin_amdgcn_mfma_f32_16x16x32_bf16(ak, bq[0][kt], s[0][t], 0, 0, 0);
        s[1][t] = __builtin_amdgcn_mfma_f32_16x16x32_bf16(ak, bq[1][kt], s[1][t], 0, 0, 0);
      }

    // softmax stats: lane holds 16 of 64 m-values for q-row n=16qf+l15 (log2 domain)
    float mx[2];
    for (int qf = 0; qf < 2; ++qf) {
      float m2 = -1e30f;
      for (int t = 0; t < 4; ++t)
        for (int r = 0; r < 4; ++r) m2 = fmaxf(m2, s[qf][t][r]);
      m2 = fmaxf(m2, __shfl_xor(m2, 16));
      m2 = fmaxf(m2, __shfl_xor(m2, 32));
      mx[qf] = m2;
    }
    if (!__all((mx[0] - mi[0] <= 8.0f) && (mx[1] - mi[1] <= 8.0f))) {
      for (int qf = 0; qf < 2; ++qf) {
        float nm = fmaxf(mi[qf], mx[qf]);
        float fac = __builtin_amdgcn_exp2f(mi[qf] - nm);
        mi[qf] = nm;
        li[qf] *= fac;
        float facb[4];
        for (int r = 0; r < 4; ++r)
          facb[r] = __shfl(fac, (lane & 48) | (l4 * 4 + r));
        for (int jt = 0; jt < 8; ++jt)
          for (int r = 0; r < 4; ++r) oacc[qf][jt][r] *= facb[r];
      }
    }
    float p[2][4][4];
    for (int qf = 0; qf < 2; ++qf) {
      float ls = 0.f;
      for (int t = 0; t < 4; ++t)
        for (int r = 0; r < 4; ++r) {
          float e = __builtin_amdgcn_exp2f(s[qf][t][r] - mi[qf]);
          p[qf][t][r] = e;
          ls += e;
        }
      ls += __shfl_xor(ls, 16);
      ls += __shfl_xor(ls, 32);
      li[qf] += ls;
    }

    // P -> per-wave LDS subtiles (parity dbuf), read back as A fragments
    int par = mt & 1;
    for (int qf = 0; qf < 2; ++qf)
      for (int t = 0; t < 4; ++t) {
        bf16x4 c4;
        for (int r = 0; r < 4; ++r) c4[r] = f2bf(p[qf][t][r]);
        *(bf16x4*)&pl[wave][qf][par][t >> 1][2 * (t & 1) + (l4 >> 1)][l15][4 * (l4 & 1)] = c4;
      }
    bf16x8 ap[2][2];
    for (int qf = 0; qf < 2; ++qf)
      for (int ks = 0; ks < 2; ++ks)
        ap[qf][ks] = *(const bf16x8*)&pl[wave][qf][par][ks][l4][l15][0];

    // PV: V direct from global (B-fragment, k-contiguous); 4 MFMA per V pair
    for (int jt = 0; jt < 8; ++jt) {
      const short* vr = v + (size_t)(jt * 16 + l15) * HWN + m0 + l4 * 8;
      bf16x8 bv0 = *(const bf16x8*)(vr);
      bf16x8 bv1 = *(const bf16x8*)(vr + 32);
      oacc[0][jt] = __builtin_amdgcn_mfma_f32_16x16x32_bf16(ap[0][0], bv0, oacc[0][jt], 0, 0, 0);
      oacc[1][jt] = __builtin_amdgcn_mfma_f32_16x16x32_bf16(ap[1][0], bv0, oacc[1][jt], 0, 0, 0);
      oacc[0][jt] = __builtin_amdgcn_mfma_f32_16x16x32_bf16(ap[0][1], bv1, oacc[0][jt], 0, 0, 0);
      oacc[1][jt] = __builtin_amdgcn_mfma_f32_16x16x32_bf16(ap[1][1], bv1, oacc[1][jt], 0, 0, 0);
    }
    __syncthreads();  // staging for mt+1 done; all waves done with Kls[cur]
  }
#undef STAGE

  // epilogue: O[n][d]/l -> Oscr[b][m=(n%8)*128+d][o=h*128+n/8]  (bijective)
  for (int qf = 0; qf < 2; ++qf) {
    float inv = 1.0f / li[qf];  // for row n = n0+16qf+l15, replicated over l4
    float invb[4];
    for (int r = 0; r < 4; ++r)
      invb[r] = __shfl(inv, (lane & 48) | (l4 * 4 + r));
    for (int jt = 0; jt < 8; ++jt) {
      int d = jt * 16 + l15;
      for (int r = 0; r < 4; ++r) {
        int n = n0 + qf * 16 + l4 * 4 + r;
        int o = h * CD + (n >> 3);
        int msp = (n & 7) * CD + d;
        Oscr[((size_t)b * HWN + msp) * 512 + o] = f2bf(oacc[qf][jt][r] * invb[r]);
      }
    }
  }
}

// ---- proj: out[b][c][m] = x + bt[c] + sum_o Wt[c][o]*OscrT[m][o] --------
__launch_bounds__(256)
__global__ void proj_kernel(const short* __restrict__ Oscr, const short* __restrict__ wtb,
                            const float* __restrict__ bt, const float* __restrict__ x,
                            float* __restrict__ out) {
  int b = blockIdx.y;
  int wave = threadIdx.x >> 6, lane = threadIdx.x & 63;
  int l15 = lane & 15, l4 = lane >> 4;
  int m0 = blockIdx.x * 64 + wave * 16;   // gridDim.x = 16

  f32x4 acc[8];
  for (int jt = 0; jt < 8; ++jt) acc[jt] = (f32x4){0.f, 0.f, 0.f, 0.f};

  const short* ob = Oscr + (size_t)b * HWN * 512;
  for (int kt = 0; kt < 16; ++kt) {
    bf16x8 a = *(const bf16x8*)(ob + (size_t)(m0 + l15) * 512 + kt * 32 + l4 * 8);
    for (int jt = 0; jt < 8; ++jt) {
      bf16x8 bw = *(const bf16x8*)(wtb + (size_t)(jt * 16 + l15) * 512 + kt * 32 + l4 * 8);
      acc[jt] = __builtin_amdgcn_mfma_f32_16x16x32_bf16(a, bw, acc[jt], 0, 0, 0);
    }
  }
  for (int jt = 0; jt < 8; ++jt) {
    int c = jt * 16 + l15;
    float btc = bt[c];
    size_t base = ((size_t)b * CD + c) * HWN + m0 + l4 * 4;
    f32x4 xr = *(const f32x4*)(x + base);
    f32x4 o;
    for (int r = 0; r < 4; ++r) o[r] = acc[jt][r] + xr[r] + btc;
    *(f32x4*)(out + base) = o;
  }
}

extern "C" void kernel_launch(void* const* d_in, const int* in_sizes, int n_in,
                              void* d_out, int out_size, void* d_ws, size_t ws_size,
                              hipStream_t stream) {
  const float* x  = (const float*)d_in[0];
  const float* Wq = (const float*)d_in[1];
  const float* Wk = (const float*)d_in[2];
  const float* Wv = (const float*)d_in[3];
  const float* bv = (const float*)d_in[4];
  const float* Wt = (const float*)d_in[5];
  const float* bt = (const float*)d_in[6];
  float* out = (float*)d_out;
  char* ws = (char*)d_ws;

  short* wqkv = (short*)(ws);
  short* wtb  = (short*)(ws + 393216);
  short* xt   = (short*)(ws + 524288);
  short* Qt   = (short*)(ws + 4718592);
  short* Kt   = (short*)(ws + 21495808);
  short* Vd   = (short*)(ws + 38273024);
  short* Oscr = (short*)(ws + 55050240);  // total 71827456 bytes

  hipLaunchKernelGGL(cvt_weights, dim3(256), dim3(256), 0, stream, Wq, Wk, Wv, Wt, wqkv, wtb);
  hipLaunchKernelGGL(cvt_transpose_x, dim3(32, 4, 16), dim3(256), 0, stream, x, xt);
  hipLaunchKernelGGL(qkv_gemm, dim3(8, 24, 16), dim3(256), 0, stream, wqkv, xt, bv, Qt, Kt, Vd);
  hipLaunchKernelGGL(attn, dim3(8, 4, 16), dim3(256), 0, stream, Qt, Kt, Vd, Oscr);
  hipLaunchKernelGGL(proj_kernel, dim3(16, 16), dim3(256), 0, stream, Oscr, wtb, bt, x, out);
}